// Round 1
// baseline (71.262 us; speedup 1.0000x reference)
//
#include <hip/hip_runtime.h>

// CRPS ensemble loss, fused single-kernel version.
//   term1 = mean_i |s_i - y|                  (per pixel)
//   term2 = 0.5 * mean_{i,j} |s_i - s_j| = (1/N^2) * sum_{i<j} |s_i - s_j|
//   out   = mean_p (term1 - term2)
// N = 16 samples, P = B*C*H*W = 262144 pixels, fp32.
//
// Structure: one thread per float2 pixel-pair; all 16 samples cached in
// registers (32 VGPRs); O(N^2) pair sum in-register. Per-block reduction
// (wave shuffle + LDS) then ONE device-scope atomicAdd per block into
// out[0], which a 4-byte memset graph node zeroes each iteration.
// vs previous version: finish kernel eliminated (one launch instead of
// two) and occupancy doubled (512 blocks -> 8 waves/CU instead of 4).

#define NS 16

__global__ __launch_bounds__(256) void crps_fused(
    const float* __restrict__ samples,
    const float* __restrict__ target,
    float* __restrict__ out,
    int P /* pixels, even */, float scale /* 1/P */) {

    const int tid = blockIdx.x * blockDim.x + threadIdx.x;  // float2-group idx
    const int P2 = P >> 1;

    float local = 0.0f;
    if (tid < P2) {
        const float2 y2 = reinterpret_cast<const float2*>(target)[tid];
        const float yv[2] = {y2.x, y2.y};

        // Cache all 16 samples for this float2 group in registers.
        // 17 independent 8B loads issued back-to-back -> full MLP.
        float s[NS][2];
#pragma unroll
        for (int i = 0; i < NS; ++i) {
            const float2 v =
                reinterpret_cast<const float2*>(samples)[(size_t)i * P2 + tid];
            s[i][0] = v.x; s[i][1] = v.y;
        }

#pragma unroll
        for (int c = 0; c < 2; ++c) {
            float sum1 = 0.0f;  // sum_i |s_i - y|
            float sum2 = 0.0f;  // sum_{i<j} |s_i - s_j|
#pragma unroll
            for (int i = 0; i < NS; ++i) {
                sum1 += fabsf(s[i][c] - yv[c]);
#pragma unroll
                for (int j = i + 1; j < NS; ++j) {
                    sum2 += fabsf(s[i][c] - s[j][c]);
                }
            }
            // term1 - term2 = sum1/N - sum2/N^2
            local += sum1 * (1.0f / (float)NS)
                   - sum2 * (1.0f / (float)(NS * NS));
        }
    }

    // wave(64) shuffle reduction
#pragma unroll
    for (int off = 32; off > 0; off >>= 1)
        local += __shfl_down(local, off, 64);

    __shared__ float wsum[4];  // 256 threads = 4 waves
    const int lane = threadIdx.x & 63;
    const int wid  = threadIdx.x >> 6;
    if (lane == 0) wsum[wid] = local;
    __syncthreads();
    if (threadIdx.x == 0) {
        const float bsum = wsum[0] + wsum[1] + wsum[2] + wsum[3];
        atomicAdd(out, bsum * scale);  // device-scope by default on gfx950
    }
}

extern "C" void kernel_launch(void* const* d_in, const int* in_sizes, int n_in,
                              void* d_out, int out_size, void* d_ws, size_t ws_size,
                              hipStream_t stream) {
    const float* samples = (const float*)d_in[0];  // [N, P]
    const float* target  = (const float*)d_in[1];  // [P]
    float* out = (float*)d_out;

    const int P  = in_sizes[1];          // 262144
    const int P2 = P >> 1;               // 131072
    const int threads = 256;
    const int blocks  = (P2 + threads - 1) / threads;  // 512

    // out[0] accumulates via atomicAdd; zero it each graph execution.
    hipMemsetAsync(d_out, 0, sizeof(float), stream);
    crps_fused<<<blocks, threads, 0, stream>>>(samples, target, out, P,
                                               1.0f / (float)P);
}